// Round 9
// baseline (284.344 us; speedup 1.0000x reference)
//
#include <hip/hip_runtime.h>
#include <hip/hip_bf16.h>
#include <math.h>

// Problem constants (fixed by setup_inputs)
#define S_LEN 4096
#define D_HID 512
#define P_DIM 512
#define H_NUM 8
#define DH 64
#define NC 64          // chunks per head (chunk = 64 rows)
#define EPS 1e-6f
#define NBLK 512       // fused kernel grid (must all be co-resident: 2/CU)

typedef __attribute__((ext_vector_type(8))) short short8;
typedef __attribute__((ext_vector_type(4))) float f32x4;
typedef __attribute__((ext_vector_type(4))) unsigned short ushort4v;

static __device__ __forceinline__ float b2f(unsigned short u) {
  return __builtin_bit_cast(float, ((unsigned int)u) << 16);
}
static __device__ __forceinline__ unsigned short f2b(float f) {
  unsigned int u = __builtin_bit_cast(unsigned int, f);
  u = (u + 0x7fff + ((u >> 16) & 1)) >> 16;  // round-nearest-even
  return (unsigned short)u;
}
// XOR swizzle: element index within a 64-elem (128B) bf16 row
static __device__ __forceinline__ int swz(int row, int d) {
  return d ^ ((row & 7) << 3);
}

#define GLOAD_LDS16(g, l)                                              \
  __builtin_amdgcn_global_load_lds(                                    \
      (const __attribute__((address_space(1))) unsigned int*)(g),      \
      (__attribute__((address_space(3))) unsigned int*)(l), 16, 0, 0)

#define MFMA16(a, b, c) __builtin_amdgcn_mfma_f32_16x16x32_bf16(a, b, c, 0, 0, 0)

#define VMCNT0 asm volatile("s_waitcnt vmcnt(0)" ::: "memory")

// Manual grid barrier: all NBLK blocks co-resident (2/CU by LDS/VGPR).
// cnt = sync[k], flag = sync[4+k]; zeroed by prep_kernel each launch.
static __device__ __forceinline__ void grid_bar(unsigned* sync, int k) {
  __syncthreads();
  if (threadIdx.x == 0) {
    __threadfence();  // writeback prior global stores (device scope)
    unsigned prev = __hip_atomic_fetch_add(sync + k, 1u, __ATOMIC_ACQ_REL,
                                           __HIP_MEMORY_SCOPE_AGENT);
    if (prev == (unsigned)(NBLK - 1)) {
      __hip_atomic_store(sync + 4 + k, 1u, __ATOMIC_RELEASE,
                         __HIP_MEMORY_SCOPE_AGENT);
    } else {
      while (__hip_atomic_load(sync + 4 + k, __ATOMIC_ACQUIRE,
                               __HIP_MEMORY_SCOPE_AGENT) == 0u) {
        __builtin_amdgcn_s_sleep(2);
      }
    }
  }
  __syncthreads();
}

// ---------------------------------------------------------------------------
// prep: zero sync cells + hs fp32->bf16 (blocks 0..2047) + weight transpose
// (blocks 2048..3071)
// ---------------------------------------------------------------------------
__global__ __launch_bounds__(256) void prep_kernel(
    const float* __restrict__ hs, const float* __restrict__ Wq,
    const float* __restrict__ Wk, const float* __restrict__ Wv,
    const float* __restrict__ Wo, unsigned short* __restrict__ hs_bf,
    unsigned short* __restrict__ WT, unsigned* __restrict__ sync) {
  __shared__ float t[32][33];
  int bid = blockIdx.x, tid = threadIdx.x;
  if (bid == 0 && tid < 8) sync[tid] = 0u;
  if (bid < 2048) {
    int idx = bid * 256 + tid;  // n4 = 524288 = 2048*256 exact
    float4 v = ((const float4*)hs)[idx];
    ushort4v o = {f2b(v.x), f2b(v.y), f2b(v.z), f2b(v.w)};
    *(ushort4v*)(hs_bf + (size_t)idx * 4) = o;
  } else {
    int b2 = bid - 2048;
    int z = b2 >> 8, r = b2 & 255;
    const float* src = (z == 0) ? Wq : (z == 1) ? Wk : (z == 2) ? Wv : Wo;
    int bx = (r & 15) * 32;  // src col block (n)
    int by = (r >> 4) * 32;  // src row block (k)
    int lx = tid & 31, ly = tid >> 5;
#pragma unroll
    for (int i = 0; i < 4; i++)
      t[ly + i * 8][lx] = src[(size_t)(by + ly + i * 8) * 512 + bx + lx];
    __syncthreads();
#pragma unroll
    for (int i = 0; i < 4; i++) {
      int n = bx + ly + i * 8;
      WT[((size_t)z * 512 + n) * 512 + by + lx] = f2b(t[lx][ly + i * 8]);
    }
  }
}

// ---------------------------------------------------------------------------
// Fused persistent kernel, 512 blocks, 3 manual grid barriers:
//  Phase 1 (h=bid&7, c=bid>>3): 64x192 projection GEMM (q|k|v), dbuf staging;
//    epilogue -> persistent LDS sqL/skL (row-major swz) + vTL/skT (transposed
//    swz); chunk-sum MFMA -> KVt fp32 + ksum (ones-row trick).
//  Phase 2 (h=bid>>6, e-row=bid&63): 4-way parallel exclusive chunk scan
//    seeded by M_mem/z_mem -> KVpz bf16 swizzled + zp_bf.
//  Phase 3 (h,c as phase 1): attention from LDS-resident sq/sk/vT + staged
//    Mp: S=sq@sk^T masked, hi/lo split; [Shi|Slo|sq]@[v|v|Mp] with ones/zp
//    col 64 -> den; attnb bf16 global.
//  Phase 4 (mb=bid>>3, nb=bid&7): 64x64 output GEMM tile attnb @ WoT -> out.
// LDS: persistent sqL 8K + skL 8K + vTL 10K + union uraw 32K = 58 KB (2/CU).
// ---------------------------------------------------------------------------
__global__ __launch_bounds__(256) void fused_kernel(
    const unsigned short* __restrict__ hs_bf,
    const unsigned short* __restrict__ WT, const float* __restrict__ bq,
    const float* __restrict__ bk, const float* __restrict__ bv,
    const float* __restrict__ M_mem, const float* __restrict__ z_mem,
    float* __restrict__ KVt, float* __restrict__ ksum,
    unsigned short* __restrict__ KVpz, unsigned short* __restrict__ zp_bf,
    unsigned short* __restrict__ attnb, float* __restrict__ outf,
    unsigned* __restrict__ sync) {
  __shared__ unsigned short sqL[64 * 64];   // 8KB persistent
  __shared__ unsigned short skL[64 * 64];   // 8KB persistent
  __shared__ unsigned short vTL[80 * 64];   // 10KB persistent (row64=ones)
  __shared__ unsigned short uraw[16384];    // 32KB phase-multiplexed

  int bid = blockIdx.x, tid = threadIdx.x;
  int w = tid >> 6, lane = tid & 63;
  int h = bid & 7, c = bid >> 3;
  int fr = lane & 15, kg8 = (lane >> 4) * 8, q4 = (lane >> 4) * 4;
  int ldrow = lane >> 2, ldk = (lane & 3) * 8;
  int wr = w >> 1, wc = w & 1;

  // ================= Phase 1: projection GEMM + chunk-sum =================
  {
    const unsigned short* Ag =
        hs_bf + (size_t)(c * 64 + w * 16 + ldrow) * 512 + ldk;
    const unsigned short* Bg =
        WT + (size_t)(h * 64 + w * 16 + ldrow) * 512 + ldk;
    // staging views: As[buf] = uraw + buf*2048; Bs[buf] = uraw+4096+buf*6144
#define PSTAGE(buf, k0)                                                   \
  do {                                                                    \
    GLOAD_LDS16(Ag + (k0), uraw + (buf)*2048 + w * 512);                  \
    GLOAD_LDS16(Bg + (k0), uraw + 4096 + (buf)*6144 + w * 512);           \
    GLOAD_LDS16(Bg + 262144 + (k0), uraw + 4096 + (buf)*6144 + 2048 + w * 512); \
    GLOAD_LDS16(Bg + 524288 + (k0), uraw + 4096 + (buf)*6144 + 4096 + w * 512); \
  } while (0)

    f32x4 acc[2][6] = {};
    PSTAGE(0, 0);
    VMCNT0;
    __builtin_amdgcn_s_barrier();
    int cur = 0;
    for (int it = 0; it < 16; it++) {
      if (it < 15) PSTAGE(cur ^ 1, (it + 1) * 32);
      short8 a[2], b[6];
#pragma unroll
      for (int m = 0; m < 2; m++)
        a[m] = *(const short8*)(uraw + cur * 2048 +
                                (wr * 32 + m * 16 + fr) * 32 + kg8);
#pragma unroll
      for (int n = 0; n < 6; n++)
        b[n] = *(const short8*)(uraw + 4096 + cur * 6144 +
                                (wc * 96 + n * 16 + fr) * 32 + kg8);
#pragma unroll
      for (int m = 0; m < 2; m++)
#pragma unroll
        for (int n = 0; n < 6; n++) acc[m][n] = MFMA16(a[m], b[n], acc[m][n]);
      VMCNT0;
      __builtin_amdgcn_s_barrier();
      cur ^= 1;
    }
#undef PSTAGE

    // epilogue: bias + activation -> persistent LDS (+ skT in uraw)
    unsigned short* skT = uraw;  // 64x64, swizzled transposed
#pragma unroll
    for (int n = 0; n < 6; n++) {
      int cl = wc * 96 + n * 16 + fr;  // 0..191
      int z = cl >> 6, d = cl & 63;
      float bias = (z == 0) ? bq[h * 64 + d]
                            : (z == 1) ? bk[h * 64 + d] : bv[h * 64 + d];
#pragma unroll
      for (int m = 0; m < 2; m++) {
#pragma unroll
        for (int j = 0; j < 4; j++) {
          int t = wr * 32 + m * 16 + q4 + j;
          float val = acc[m][n][j] + bias;
          if (z < 2) val = (val > 0.f) ? (val + 1.f) : __expf(val);
          unsigned short bb = f2b(val);
          if (z == 0) {
            sqL[t * 64 + swz(t, d)] = bb;
          } else if (z == 1) {
            skL[t * 64 + swz(t, d)] = bb;
            skT[d * 64 + swz(d, t)] = bb;
          } else {
            vTL[d * 64 + swz(d, t)] = bb;
          }
        }
      }
    }
    if (tid < 8) {  // vTL row 64 = ones (denominator intra column)
      short8 one;
#pragma unroll
      for (int j = 0; j < 8; j++) one[j] = (short)0x3F80;
      *(short8*)(vTL + 64 * 64 + tid * 8) = one;
    }
    if (tid < 120) {  // zero vTL rows 65..79
      short8 zz = {};
      *(short8*)(vTL + 65 * 64 + tid * 8) = zz;
    }
    __syncthreads();

    // chunk-sum MFMA: KVt[e][d] = sum_t v[t][e]*sk[t][d]; ksum via ones-A
    short8 onesA = {};
    if (fr == 0) {
#pragma unroll
      for (int j = 0; j < 8; j++) onesA[j] = (short)0x3F80;
    }
    f32x4 accC[4] = {}, accKk[4] = {};
#pragma unroll
    for (int k0 = 0; k0 < 64; k0 += 32) {
      int e = w * 16 + fr;
      short8 a2 =
          *(const short8*)(vTL + e * 64 + ((k0 + kg8) ^ ((e & 7) << 3)));
#pragma unroll
      for (int nt = 0; nt < 4; nt++) {
        int d = nt * 16 + fr;
        short8 b2 =
            *(const short8*)(skT + d * 64 + ((k0 + kg8) ^ ((d & 7) << 3)));
        accC[nt] = MFMA16(a2, b2, accC[nt]);
        if (w == 0) accKk[nt] = MFMA16(onesA, b2, accKk[nt]);
      }
    }
    size_t base = (size_t)(h * NC + c) * 4096;
    int e0 = w * 16 + q4;
#pragma unroll
    for (int nt = 0; nt < 4; nt++)
#pragma unroll
      for (int j = 0; j < 4; j++)
        KVt[base + (size_t)(e0 + j) * 64 + nt * 16 + fr] = accC[nt][j];
    if (w == 0 && lane < 16) {
#pragma unroll
      for (int nt = 0; nt < 4; nt++)
        ksum[(size_t)(h * NC + c) * 64 + nt * 16 + lane] = accKk[nt][0];
    }
  }

  grid_bar(sync, 0);

  // ================= Phase 2: parallel exclusive chunk scan ===============
  {
    float* p = (float*)uraw;        // 256 floats
    float* zz = p + 256;            // 256 floats
    int h2 = bid >> 6, seg = bid & 63;
    int d = tid & 63, q = tid >> 6;
    size_t ebase = (size_t)h2 * NC * 4096 + (size_t)seg * 64 + d;
    float part = 0.f;
#pragma unroll 4
    for (int i = 0; i < 16; i++)
      part += KVt[ebase + (size_t)(q * 16 + i) * 4096];
    p[d * 4 + q] = part;
    if (seg == 0) {
      size_t zb = (size_t)h2 * NC * 64 + d;
      float pz = 0.f;
#pragma unroll 4
      for (int i = 0; i < 16; i++) pz += ksum[zb + (size_t)(q * 16 + i) * 64];
      zz[d * 4 + q] = pz;
    }
    __syncthreads();
    float pref = M_mem[h2 * 4096 + d * 64 + seg];  // M_mem[h][d][e]
    for (int q2 = 0; q2 < q; q2++) pref += p[d * 4 + q2];
    int sw = swz(seg, d);
#pragma unroll 4
    for (int i = 0; i < 16; i++) {
      int cc = q * 16 + i;
      KVpz[(size_t)(h2 * NC + cc) * 4096 + seg * 64 + sw] = f2b(pref);
      pref += KVt[ebase + (size_t)cc * 4096];
    }
    if (seg == 0) {
      float bz = z_mem[h2 * 64 + d];
      for (int q2 = 0; q2 < q; q2++) bz += zz[d * 4 + q2];
      size_t zb = (size_t)h2 * NC * 64 + d;
#pragma unroll 4
      for (int i = 0; i < 16; i++) {
        int cc = q * 16 + i;
        zp_bf[zb + (size_t)cc * 64] = f2b(bz);
        bz += ksum[zb + (size_t)cc * 64];
      }
    }
  }

  grid_bar(sync, 1);

  // ================= Phase 3: attention (LDS-resident sq/sk/vT) ===========
  {
    unsigned short* btm = uraw;          // 80x64 = 5120 sh
    unsigned short* shi = uraw + 5120;   // 64x64
    unsigned short* slo = uraw + 9216;   // 64x64
    const unsigned short* km_g = KVpz + (size_t)(h * NC + c) * 4096;
#pragma unroll
    for (int i = 0; i < 2; i++) {
      int seg2 = w * 2 + i;
      GLOAD_LDS16(km_g + seg2 * 512 + lane * 8, btm + seg2 * 512);
    }
    if (tid < 8)
      *(short8*)(btm + 64 * 64 + tid * 8) =
          *(const short8*)(zp_bf + (size_t)(h * NC + c) * 64 + tid * 8);

    int ta = w * 16 + fr, sw_a = (ta & 7) << 3;
    // stage 1: S = sq @ sk^T
    f32x4 accS[4] = {};
#pragma unroll
    for (int k0 = 0; k0 < 64; k0 += 32) {
      short8 a = *(const short8*)(sqL + ta * 64 + ((k0 + kg8) ^ sw_a));
#pragma unroll
      for (int nt = 0; nt < 4; nt++) {
        int tp = nt * 16 + fr;
        short8 b =
            *(const short8*)(skL + tp * 64 + ((k0 + kg8) ^ ((tp & 7) << 3)));
        accS[nt] = MFMA16(a, b, accS[nt]);
      }
    }
    // mask + hi/lo split (own rows only)
#pragma unroll
    for (int nt = 0; nt < 4; nt++) {
      int tp = nt * 16 + fr;
#pragma unroll
      for (int j = 0; j < 4; j++) {
        int t = w * 16 + q4 + j;
        float s = (tp <= t) ? accS[nt][j] : 0.f;
        unsigned short hi = f2b(s);
        unsigned short lo = f2b(s - b2f(hi));
        shi[t * 64 + swz(t, tp)] = hi;
        slo[t * 64 + swz(t, tp)] = lo;
      }
    }
    __syncthreads();  // drains btm gload + zp write + shi/slo
    // stage 2: [Shi|Slo|sq] @ [v|v|Mp]
    f32x4 acc2[5] = {};
#pragma unroll
    for (int ks = 0; ks < 6; ks++) {
      const unsigned short* asrc = (ks < 2) ? shi : (ks < 4) ? slo : sqL;
      const unsigned short* bsrc = (ks < 4) ? vTL : btm;
      int ak = (ks & 1) * 32 + kg8;
      short8 a = *(const short8*)(asrc + ta * 64 + (ak ^ sw_a));
#pragma unroll
      for (int nt = 0; nt < 5; nt++) {
        int n = nt * 16 + fr;
        short8 b = *(const short8*)(bsrc + n * 64 + (ak ^ ((n & 7) << 3)));
        acc2[nt] = MFMA16(a, b, acc2[nt]);
      }
    }
    float inv[4];
#pragma unroll
    for (int j = 0; j < 4; j++) {
      float dj = __shfl(acc2[4][j], (lane & 48), 64);
      inv[j] = 1.f / (dj + EPS);
    }
    int srow = c * 64 + w * 16 + q4;
#pragma unroll
    for (int nt = 0; nt < 4; nt++) {
      int col = h * 64 + nt * 16 + fr;
#pragma unroll
      for (int j = 0; j < 4; j++)
        attnb[(size_t)(srow + j) * 512 + col] = f2b(acc2[nt][j] * inv[j]);
    }
  }

  grid_bar(sync, 2);

  // ================= Phase 4: output GEMM 64x64 tile ======================
  {
    int bm = (bid >> 3) * 64, bn = (bid & 7) * 64;
    const unsigned short* WoT = WT + (size_t)3 * 512 * 512;
    const unsigned short* Ag =
        attnb + (size_t)(bm + w * 16 + ldrow) * 512 + ldk;
    const unsigned short* Bg =
        WoT + (size_t)(bn + w * 16 + ldrow) * 512 + ldk;
    // As4[buf] = uraw + buf*2048; Bs4[buf] = uraw + 4096 + buf*2048
#define OSTAGE(buf, k0)                                          \
  do {                                                           \
    GLOAD_LDS16(Ag + (k0), uraw + (buf)*2048 + w * 512);         \
    GLOAD_LDS16(Bg + (k0), uraw + 4096 + (buf)*2048 + w * 512);  \
  } while (0)

    f32x4 acc4[2][2] = {};
    OSTAGE(0, 0);
    VMCNT0;
    __builtin_amdgcn_s_barrier();
    int cur = 0;
    for (int it = 0; it < 16; it++) {
      if (it < 15) OSTAGE(cur ^ 1, (it + 1) * 32);
      short8 a[2], b[2];
#pragma unroll
      for (int m = 0; m < 2; m++)
        a[m] = *(const short8*)(uraw + cur * 2048 +
                                (wr * 32 + m * 16 + fr) * 32 + kg8);
#pragma unroll
      for (int n = 0; n < 2; n++)
        b[n] = *(const short8*)(uraw + 4096 + cur * 2048 +
                                (wc * 32 + n * 16 + fr) * 32 + kg8);
#pragma unroll
      for (int m = 0; m < 2; m++)
#pragma unroll
        for (int n = 0; n < 2; n++) acc4[m][n] = MFMA16(a[m], b[n], acc4[m][n]);
      VMCNT0;
      __builtin_amdgcn_s_barrier();
      cur ^= 1;
    }
#undef OSTAGE
#pragma unroll
    for (int m = 0; m < 2; m++) {
      int row0 = bm + wr * 32 + m * 16 + q4;
#pragma unroll
      for (int n = 0; n < 2; n++) {
        int col = bn + wc * 32 + n * 16 + fr;
#pragma unroll
        for (int j = 0; j < 4; j++)
          outf[(size_t)(row0 + j) * 512 + col] = acc4[m][n][j];
      }
    }
  }
}

// ---------------------------------------------------------------------------
extern "C" void kernel_launch(void* const* d_in, const int* in_sizes, int n_in,
                              void* d_out, int out_size, void* d_ws,
                              size_t ws_size, hipStream_t stream) {
  const float* hs = (const float*)d_in[0];
  const float* Wq = (const float*)d_in[1];
  const float* bq = (const float*)d_in[2];
  const float* Wk = (const float*)d_in[3];
  const float* bk = (const float*)d_in[4];
  const float* Wv = (const float*)d_in[5];
  const float* bv = (const float*)d_in[6];
  const float* Wo = (const float*)d_in[7];
  const float* M_mem = (const float*)d_in[8];
  const float* z_mem = (const float*)d_in[9];
  float* out = (float*)d_out;

  unsigned short* hs_bf = (unsigned short*)d_ws;            // 2M sh
  unsigned short* WT = hs_bf + (size_t)S_LEN * D_HID;       // 1M sh
  unsigned short* attnb = WT + (size_t)4 * 512 * 512;       // 2M sh
  unsigned short* KVpz = attnb + (size_t)S_LEN * P_DIM;     // 2M sh
  unsigned short* zp_bf = KVpz + (size_t)H_NUM * NC * DH * DH;  // 32K sh
  float* KVt = (float*)(zp_bf + (size_t)H_NUM * NC * DH);       // 2M f
  float* ksum = KVt + (size_t)H_NUM * NC * DH * DH;             // 32K f
  unsigned* sync = (unsigned*)(ksum + (size_t)H_NUM * NC * DH); // 8 u32

  prep_kernel<<<3072, 256, 0, stream>>>(hs, Wq, Wk, Wv, Wo, hs_bf, WT, sync);

  fused_kernel<<<NBLK, 256, 0, stream>>>(hs_bf, WT, bq, bk, bv, M_mem, z_mem,
                                         KVt, ksum, KVpz, zp_bf, attnb, out,
                                         sync);
}